// Round 7
// baseline (1519.739 us; speedup 1.0000x reference)
//
#include <hip/hip_runtime.h>
#include <cstdint>

// ---------------- problem constants ----------------
#define NYD   256
#define NXD   256
#define PADC  22            // PML + FD_PAD
#define NYP_  300           // NY + 2*PAD
#define NXP_  300
#define NTT   250
#define NSHOT_ 2
#define NSRC_  8
#define NREC_  64
#define DT_   0.0005f

// guarded-array geometry
#define GDN   28
#define STP   356           // NXP_ + 2*GDN
#define FP    (STP*STP)     // per-shot field words

// fallback (r5) tile geometry: 64x4, 750 blocks
#define NTX   5
#define TPS   375
#define NWG   750

// persistent tile geometry: 64x16, 190 blocks of 512 threads
#define BY2   16
#define NTY2  19            // ceil(300/16)
#define TPS2  95            // 19*5 per shot
#define NWG2  190

// ---------------- agent-scope (cross-XCD coherent) access helpers ----------------
__device__ __forceinline__ unsigned long long ld_agent_u64(const float* p) {
    return __hip_atomic_load((const unsigned long long*)p,
                             __ATOMIC_RELAXED, __HIP_MEMORY_SCOPE_AGENT);
}
__device__ __forceinline__ void st_agent_f32(float* p, float v) {
    __hip_atomic_store((unsigned*)p, __float_as_uint(v),
                       __ATOMIC_RELAXED, __HIP_MEMORY_SCOPE_AGENT);
}

// ---------------- zero workspace ----------------
__global__ void zero_kernel(float* __restrict__ p, long n) {
    long i = (long)blockIdx.x * blockDim.x + threadIdx.x;
    long stride = (long)gridDim.x * blockDim.x;
    for (; i < n; i += stride) p[i] = 0.0f;
}

// ---------------- setup: v2dt2, PML profiles, src/rec tile bins (both geometries) ----------------
__global__ void populate_kernel(const float* __restrict__ v,
                                const int* __restrict__ srcloc,
                                const int* __restrict__ recloc,
                                float* __restrict__ v2dt2,
                                float* __restrict__ prof,
                                unsigned* __restrict__ srcb4,
                                unsigned long long* __restrict__ recb4,
                                unsigned* __restrict__ srcb16,
                                unsigned long long* __restrict__ recb16) {
    int i = blockIdx.x * 256 + threadIdx.x;

    if (i < NYP_ * NXP_) {
        int y = i / NXP_, x = i % NXP_;
        int vy = min(max(y - PADC, 0), NYD - 1);
        int vx = min(max(x - PADC, 0), NXD - 1);
        float vv = v[vy * NXD + vx];
        v2dt2[(y + GDN) * STP + (x + GDN)] = vv * vv * (DT_ * DT_);
    }

    if (i < NYP_) {
        float fi = (float)i;
        float d = fmaxf(22.0f - fi, fi - 277.0f);
        float frac = fminf(fmaxf(d * (1.0f / 20.0f), 0.0f), 1.0f);
        float sigma_max = 3.0f * 4000.0f * logf(1000.0f) / (2.0f * 20.0f * 5.0f);
        float sigma = sigma_max * frac * frac;
        float alpha = 3.14159265358979323846f * 25.0f * (1.0f - frac);
        float b = expf(-(sigma + alpha) * DT_);
        float a = sigma / (sigma + alpha + 1e-9f) * (b - 1.0f);
        prof[GDN + i] = a;
        prof[STP + GDN + i] = b;
    }

    if (i < NSHOT_ * NSRC_) {
        int sy = srcloc[2 * i] + PADC;
        int sx = srcloc[2 * i + 1] + PADC;
        int shot = i / NSRC_;
        atomicOr(&srcb4[shot * TPS + (sy / 4) * NTX + (sx / 64)], 1u << (i % NSRC_));
        atomicOr(&srcb16[shot * TPS2 + (sy / BY2) * 5 + (sx / 64)], 1u << (i % NSRC_));
    }

    if (i >= 1024 && i < 1024 + NSHOT_ * NREC_) {
        int j = i - 1024;
        int ry = recloc[2 * j] + PADC;
        int rx = recloc[2 * j + 1] + PADC;
        int shot = j / NREC_;
        atomicOr(&recb4[shot * TPS + (ry / 4) * NTX + (rx / 64)], 1ull << (j % NREC_));
        atomicOr(&recb16[shot * TPS2 + (ry / BY2) * 5 + (rx / 64)], 1ull << (j % NREC_));
    }
}

// ---------------- persistent kernel: all 250 steps, neighbor-only sync ----------------
// 190 blocks (16x64 tiles, 2 shots), 512 threads, 2 cells/thread. Co-residency
// guaranteed by cooperative launch (<=1 block/CU). Per step: wait 4 neighbor
// flags >= it (data-ready AND overwrite-safe; neighbors run in lockstep, no
// deadlock); stage wf/psi (8B agent-scope loads -> LDS); compute (math
// identical to verified r5 kernel; zeta/wfm/v2 in registers); publish tiles
// (agent-scope 4B stores -> coherence point, no L2 flush); vmcnt(0)+barrier;
// post flag. Cross-stencil => 4 neighbors suffice (staged wf corners unused).
// Guard ring (all-zero, prof/v2 zero) keeps Dirichlet exact; overhang cells
// publish exact zeros forever.
__global__ __launch_bounds__(512) void persist_kernel(
    float* wfA, float* wfB, float* pyA, float* pyB, float* pxA, float* pxB,
    const float* __restrict__ v2g, const float* __restrict__ profg,
    const unsigned* __restrict__ srcb, const unsigned long long* __restrict__ recb,
    int* prog,
    const int* __restrict__ srcloc, const int* __restrict__ recloc,
    const float* __restrict__ amps,   // [NSHOT][NSRC][NT]
    float* __restrict__ out) {        // [NSHOT][NREC][NT]
    const int me   = blockIdx.x;
    const int shot = me / TPS2;
    const int tl   = me - shot * TPS2;
    const int tyt  = tl / 5, txt = tl % 5;
    const int ty0  = tyt * BY2, tx0 = txt * 64;

    const int nUp = (tyt > 0)        ? me - 5 : me;
    const int nDn = (tyt < NTY2 - 1) ? me + 5 : me;
    const int nL  = (txt > 0)        ? me - 1 : me;
    const int nR  = (txt < 4)        ? me + 1 : me;

    __shared__ alignas(8) float swf[24][72];   // wf: rows ty0-4..+19, cols tx0-4..+67
    __shared__ alignas(8) float spy[20][64];   // psiy: rows ty0-2..+17, cols tx0..+63
    __shared__ alignas(8) float spx[16][72];   // psix: rows ty0..+15, cols tx0-4..+67
    __shared__ float sya[20], syb[20], sxa[68], sxb[68];
    __shared__ int   ssy[NSRC_], ssx[NSRC_], sry[NREC_], srx[NREC_];
    __shared__ unsigned sbs;
    __shared__ unsigned long long sbr;

    const int tid = threadIdx.x;
    const int lx = tid & 63, ly = tid >> 6;    // cells: yy = ly and ly+8

    if (tid < 20) {
        sya[tid] = profg[GDN + ty0 - 2 + tid];
        syb[tid] = profg[STP + GDN + ty0 - 2 + tid];
    }
    if (tid < 68) {
        sxa[tid] = profg[GDN + tx0 - 2 + tid];
        sxb[tid] = profg[STP + GDN + tx0 - 2 + tid];
    }
    if (tid < NSRC_) {
        ssy[tid] = srcloc[(shot * NSRC_ + tid) * 2]     + PADC;
        ssx[tid] = srcloc[(shot * NSRC_ + tid) * 2 + 1] + PADC;
    }
    if (tid < NREC_) {
        sry[tid] = recloc[(shot * NREC_ + tid) * 2]     + PADC;
        srx[tid] = recloc[(shot * NREC_ + tid) * 2 + 1] + PADC;
    }
    if (tid == 0) { sbs = srcb[shot * TPS2 + tl]; sbr = recb[shot * TPS2 + tl]; }

    float zyr[2] = {0.f, 0.f}, zxr[2] = {0.f, 0.f}, wmr[2] = {0.f, 0.f}, vdr[2];
#pragma unroll
    for (int c = 0; c < 2; ++c)
        vdr[c] = v2g[(ty0 + ly + 8 * c + GDN) * STP + (tx0 + lx + GDN)];

    const float* wfr = wfA + shot * FP;  float* wfw = wfB + shot * FP;
    const float* pyr = pyA + shot * FP;  float* pyw = pyB + shot * FP;
    const float* pxr = pxA + shot * FP;  float* pxw = pxB + shot * FP;

    __syncthreads();

    const float ih  = 0.2f;    // 1/DY
    const float ih2 = 0.04f;   // 1/DY^2
    const float C1A = 2.0f / 3.0f, C1B = 1.0f / 12.0f;
    const float C2A = 4.0f / 3.0f, C2B = -1.0f / 12.0f, C2C = -2.5f;

#pragma unroll 1
    for (int it = 0; it < NTT; ++it) {
        // ---- wait: neighbors published state for step it ----
        if (tid < 4) {
            const int nb = (tid == 0) ? nUp : (tid == 1) ? nDn : (tid == 2) ? nL : nR;
            while (__hip_atomic_load(&prog[nb], __ATOMIC_RELAXED, __HIP_MEMORY_SCOPE_AGENT) < it)
                __builtin_amdgcn_s_sleep(1);
        }
        __syncthreads();

        // ---- stage (agent-scope 8B loads; 2080 items / 512 threads) ----
#pragma unroll
        for (int li = 0; li < 5; ++li) {
            int lin = tid + li * 512;
            if (lin < 864) {                   // swf: 24 x 36
                int rr = lin / 36, cc = lin % 36;
                *(unsigned long long*)&swf[rr][cc * 2] =
                    ld_agent_u64(wfr + (ty0 - 4 + rr + GDN) * STP + (tx0 - 4 + GDN) + cc * 2);
            } else if (lin < 1504) {           // spy: 20 x 32
                int l = lin - 864, rr = l / 32, cc = l % 32;
                *(unsigned long long*)&spy[rr][cc * 2] =
                    ld_agent_u64(pyr + (ty0 - 2 + rr + GDN) * STP + (tx0 + GDN) + cc * 2);
            } else if (lin < 2080) {           // spx: 16 x 36
                int l = lin - 1504, rr = l / 36, cc = l % 36;
                *(unsigned long long*)&spx[rr][cc * 2] =
                    ld_agent_u64(pxr + (ty0 + rr + GDN) * STP + (tx0 - 4 + GDN) + cc * 2);
            }
        }
        __syncthreads();

        // ---- compute + publish (2 cells/thread, r5 math verbatim) ----
#pragma unroll
        for (int c = 0; c < 2; ++c) {
            const int yy = ly + 8 * c;
            const int y = ty0 + yy, x = tx0 + lx;

            float wy[9], wx[9];
#pragma unroll
            for (int k = 0; k < 9; ++k) wy[k] = swf[yy + k][lx + 4];
#pragma unroll
            for (int k = 0; k < 9; ++k) wx[k] = (k == 4) ? wy[4] : swf[yy + 4][lx + k];

            float d2y = (C2B * (wy[2] + wy[6]) + C2A * (wy[3] + wy[5]) + C2C * wy[4]) * ih2;
            float d2x = (C2B * (wx[2] + wx[6]) + C2A * (wx[3] + wx[5]) + C2C * wx[4]) * ih2;

            float pny[5], pnx[5];
#pragma unroll
            for (int j = 0; j < 5; ++j) {
                float dwdy = (C1A * (wy[j + 3] - wy[j + 1]) - C1B * (wy[j + 4] - wy[j])) * ih;
                pny[j] = syb[yy + j] * spy[yy + j][lx] + sya[yy + j] * dwdy;
                float dwdx = (C1A * (wx[j + 3] - wx[j + 1]) - C1B * (wx[j + 4] - wx[j])) * ih;
                pnx[j] = sxb[lx + j] * spx[yy][lx + j + 2] + sxa[lx + j] * dwdx;
            }
            float dpsiy = (C1A * (pny[3] - pny[1]) - C1B * (pny[4] - pny[0])) * ih;
            float dpsix = (C1A * (pnx[3] - pnx[1]) - C1B * (pnx[4] - pnx[0])) * ih;

            float zyn = syb[yy + 2] * zyr[c] + sya[yy + 2] * (d2y + dpsiy);
            float zxn = sxb[lx + 2] * zxr[c] + sxa[lx + 2] * (d2x + dpsix);
            zyr[c] = zyn; zxr[c] = zxn;

            float lap = d2y + d2x + dpsiy + dpsix + zyn + zxn;
            float wfp = 2.0f * wy[4] - wmr[c] + vdr[c] * lap;

            if (sbs) {
#pragma unroll
                for (int q = 0; q < NSRC_; ++q)
                    if ((sbs & (1u << q)) && ssy[q] == y && ssx[q] == x)
                        wfp += vdr[c] * amps[(shot * NSRC_ + q) * NTT + it];
            }
            wmr[c] = wy[4];

            const int g = (y + GDN) * STP + (x + GDN);
            st_agent_f32(wfw + g, wfp);
            st_agent_f32(pyw + g, pny[2]);
            st_agent_f32(pxw + g, pnx[2]);

            unsigned long long rb = sbr;
            while (rb) {
                int r = __ffsll(rb) - 1;
                rb &= rb - 1;
                if (sry[r] == y && srx[r] == x)
                    out[(shot * NREC_ + r) * NTT + it] = wfp;
            }
        }

        // ---- drain publishes, then post flag ----
        asm volatile("s_waitcnt vmcnt(0)" ::: "memory");
        __syncthreads();
        if (tid == 0)
            __hip_atomic_store(&prog[me], it + 1, __ATOMIC_RELAXED, __HIP_MEMORY_SCOPE_AGENT);

        const float* t0 = wfr; wfr = wfw; wfw = (float*)t0;
        const float* t1 = pyr; pyr = pyw; pyw = (float*)t1;
        const float* t2 = pxr; pxr = pxw; pxw = (float*)t2;
    }
}

// ---------------- fallback: verified r5 single-step kernel ----------------
__global__ __launch_bounds__(256) void step_kernel(
    const float* __restrict__ wfc_g, float* __restrict__ wfn_g,
    const float* __restrict__ pyr_g, float* __restrict__ pyw_g,
    const float* __restrict__ pxr_g, float* __restrict__ pxw_g,
    float* __restrict__ zy_g, float* __restrict__ zx_g,
    const float* __restrict__ v2_g, const float* __restrict__ prof,
    const unsigned* __restrict__ srcbin,
    const unsigned long long* __restrict__ recbin,
    const int* __restrict__ srcloc, const int* __restrict__ recloc,
    const float* __restrict__ amps, float* __restrict__ out, int t) {
    int orig = blockIdx.x;
    int xcd = orig & 7, idx = orig >> 3;
    int wgid = (xcd < 6) ? xcd * 94 + idx : 6 * 94 + (xcd - 6) * 93 + idx;
    int shot = wgid / TPS;
    int tl   = wgid - shot * TPS;
    int ty0  = (tl / NTX) * 4;
    int tx0  = (tl % NTX) * 64;

    const float* wfc = wfc_g + shot * FP;
    float*       wfn = wfn_g + shot * FP;
    const float* pyr = pyr_g + shot * FP;
    float*       pyw = pyw_g + shot * FP;
    const float* pxr = pxr_g + shot * FP;
    float*       pxw = pxw_g + shot * FP;
    float*       zyg = zy_g  + shot * FP;
    float*       zxg = zx_g  + shot * FP;

    __shared__ float swf[12][72];
    __shared__ float spy[8][64];
    __shared__ float spx[4][72];
    __shared__ float sya[8], syb[8], sxa[68], sxb[68];
    __shared__ int   ssy[NSRC_], ssx[NSRC_], sry[NREC_], srx[NREC_];
    __shared__ unsigned sbs;
    __shared__ unsigned long long sbr;

    const int tid = threadIdx.x;
    const int lx = tid & 63, ly = tid >> 6;
    const int y = ty0 + ly, x = tx0 + lx;
    const int g = (y + GDN) * STP + (x + GDN);

    float wm = wfn[g];
    float zy = zyg[g];
    float zx = zxg[g];
    float vd = v2_g[g];

    if (tid < 216) {
        int rr = tid / 18, cc = tid % 18;
        *reinterpret_cast<float4*>(&swf[rr][cc * 4]) =
            *(reinterpret_cast<const float4*>(wfc + (ty0 - 4 + rr + GDN) * STP + (tx0 - 4 + GDN)) + cc);
    }
    if (tid < 128) {
        int rr = tid / 16, cc = tid % 16;
        *reinterpret_cast<float4*>(&spy[rr][cc * 4]) =
            *(reinterpret_cast<const float4*>(pyr + (ty0 - 2 + rr + GDN) * STP + (tx0 + GDN)) + cc);
    }
    if (tid < 72) {
        int rr = tid / 18, cc = tid % 18;
        *reinterpret_cast<float4*>(&spx[rr][cc * 4]) =
            *(reinterpret_cast<const float4*>(pxr + (ty0 + rr + GDN) * STP + (tx0 - 4 + GDN)) + cc);
    }
    if (tid < 8) {
        sya[tid] = prof[GDN + ty0 - 2 + tid];
        syb[tid] = prof[STP + GDN + ty0 - 2 + tid];
        ssy[tid] = srcloc[(shot * NSRC_ + tid) * 2]     + PADC;
        ssx[tid] = srcloc[(shot * NSRC_ + tid) * 2 + 1] + PADC;
    }
    if (tid < 68) {
        sxa[tid] = prof[GDN + tx0 - 2 + tid];
        sxb[tid] = prof[STP + GDN + tx0 - 2 + tid];
    }
    if (tid < NREC_) {
        sry[tid] = recloc[(shot * NREC_ + tid) * 2]     + PADC;
        srx[tid] = recloc[(shot * NREC_ + tid) * 2 + 1] + PADC;
    }
    if (tid == 0) { sbs = srcbin[shot * TPS + tl]; sbr = recbin[shot * TPS + tl]; }
    __syncthreads();

    const float ih = 0.2f, ih2 = 0.04f;
    const float C1A = 2.0f / 3.0f, C1B = 1.0f / 12.0f;
    const float C2A = 4.0f / 3.0f, C2B = -1.0f / 12.0f, C2C = -2.5f;

    float wy[9];
#pragma unroll
    for (int k = 0; k < 9; k++) wy[k] = swf[ly + k][lx + 4];
    float wx[9];
#pragma unroll
    for (int k = 0; k < 9; k++) wx[k] = (k == 4) ? wy[4] : swf[ly + 4][lx + k];

    float d2y = (C2B * (wy[2] + wy[6]) + C2A * (wy[3] + wy[5]) + C2C * wy[4]) * ih2;
    float d2x = (C2B * (wx[2] + wx[6]) + C2A * (wx[3] + wx[5]) + C2C * wx[4]) * ih2;

    float pny[5], pnx[5];
#pragma unroll
    for (int j = 0; j < 5; j++) {
        float dwdy = (C1A * (wy[j + 3] - wy[j + 1]) - C1B * (wy[j + 4] - wy[j])) * ih;
        pny[j] = syb[ly + j] * spy[ly + j][lx] + sya[ly + j] * dwdy;
        float dwdx = (C1A * (wx[j + 3] - wx[j + 1]) - C1B * (wx[j + 4] - wx[j])) * ih;
        pnx[j] = sxb[lx + j] * spx[ly][lx + j + 2] + sxa[lx + j] * dwdx;
    }

    float dpsiy = (C1A * (pny[3] - pny[1]) - C1B * (pny[4] - pny[0])) * ih;
    float dpsix = (C1A * (pnx[3] - pnx[1]) - C1B * (pnx[4] - pnx[0])) * ih;

    float ay_ = sya[ly + 2], by_ = syb[ly + 2];
    float ax_ = sxa[lx + 2], bx_ = sxb[lx + 2];

    zy = by_ * zy + ay_ * (d2y + dpsiy);
    zx = bx_ * zx + ax_ * (d2x + dpsix);

    float lap = d2y + d2x + dpsiy + dpsix + zy + zx;
    float wfp = 2.0f * wy[4] - wm + vd * lap;

    if (sbs) {
#pragma unroll
        for (int q = 0; q < NSRC_; q++)
            if ((sbs & (1u << q)) && ssy[q] == y && ssx[q] == x)
                wfp += vd * amps[(shot * NSRC_ + q) * NTT + t];
    }

    wfn[g] = wfp;
    pyw[g] = pny[2];
    pxw[g] = pnx[2];
    zyg[g] = zy;
    zxg[g] = zx;

    unsigned long long rb = sbr;
    while (rb) {
        int r = __ffsll(rb) - 1;
        rb &= rb - 1;
        if (sry[r] == y && srx[r] == x)
            out[(shot * NREC_ + r) * NTT + t] = wfp;
    }
}

// ---------------- host ----------------
extern "C" void kernel_launch(void* const* d_in, const int* in_sizes, int n_in,
                              void* d_out, int out_size, void* d_ws, size_t ws_size,
                              hipStream_t stream) {
    const float* v      = (const float*)d_in[0];
    const float* amps   = (const float*)d_in[1];
    const int*   srcloc = (const int*)d_in[2];
    const int*   recloc = (const int*)d_in[3];
    float* out = (float*)d_out;

    float* base = (float*)d_ws;
    float* WF0 = base;
    float* WF1 = WF0 + 2L * FP;
    float* PY0 = WF1 + 2L * FP;
    float* PY1 = PY0 + 2L * FP;
    float* PX0 = PY1 + 2L * FP;
    float* PX1 = PX0 + 2L * FP;
    float* ZY  = PX1 + 2L * FP;    // fallback only
    float* ZX  = ZY  + 2L * FP;    // fallback only
    float* V2  = ZX  + 2L * FP;
    float* PROF = V2 + FP;         // [2*STP]
    unsigned long long* RECB4  = (unsigned long long*)(PROF + 2 * STP);   // 750 ull
    unsigned long long* RECB16 = RECB4 + NSHOT_ * TPS;                    // 190 ull
    unsigned* SRCB4  = (unsigned*)(RECB16 + NSHOT_ * TPS2);               // 750 u32
    unsigned* SRCB16 = SRCB4 + NSHOT_ * TPS;                              // 190 u32
    int*      PROG   = (int*)(SRCB16 + NSHOT_ * TPS2);                    // 190 int

    const long total_words = 17L * FP + 2 * STP
                           + 2L * NSHOT_ * TPS + 2L * NSHOT_ * TPS2   // rec bins (words)
                           + NSHOT_ * TPS + NSHOT_ * TPS2             // src bins
                           + NWG2;                                    // prog

    zero_kernel<<<2048, 256, 0, stream>>>(base, total_words);
    populate_kernel<<<(NYP_ * NXP_ + 255) / 256, 256, 0, stream>>>(
        v, srcloc, recloc, V2, PROF, SRCB4, RECB4, SRCB16, RECB16);

    // ---- preferred: one persistent cooperative kernel, neighbor-only sync ----
    void* args[] = {
        (void*)&WF0, (void*)&WF1, (void*)&PY0, (void*)&PY1, (void*)&PX0, (void*)&PX1,
        (void*)&V2, (void*)&PROF, (void*)&SRCB16, (void*)&RECB16, (void*)&PROG,
        (void*)&srcloc, (void*)&recloc, (void*)&amps, (void*)&out
    };
    hipError_t e = hipLaunchCooperativeKernel((void*)persist_kernel,
                                              dim3(NWG2), dim3(512), args, 0, stream);

    // ---- fallback: verified r5 250-launch loop ----
    if (e != hipSuccess) {
        for (int t = 0; t < NTT; t++) {
            const bool o = (t & 1);
            step_kernel<<<NWG, 256, 0, stream>>>(
                o ? WF1 : WF0, o ? WF0 : WF1,
                o ? PY1 : PY0, o ? PY0 : PY1,
                o ? PX1 : PX0, o ? PX0 : PX1,
                ZY, ZX, V2, PROF, SRCB4, RECB4,
                srcloc, recloc, amps, out, t);
        }
    }
}